// Round 9
// baseline (2800.540 us; speedup 1.0000x reference)
//
#include <hip/hip_runtime.h>
#include <hip/hip_bf16.h>

#define LRELU(e) ((e) > 0.f ? (e) : 0.2f * (e))

typedef __attribute__((ext_vector_type(8))) short bf16x8;
typedef __attribute__((ext_vector_type(4))) float floatx4;

__device__ inline short f2bf(float f) {
    union { float f; unsigned u; } v; v.f = f;
    unsigned r = v.u + 0x7fffu + ((v.u >> 16) & 1u);
    return (short)(r >> 16);
}
__device__ inline float bflo(int p) {
    union { unsigned u; float f; } v; v.u = (unsigned)p << 16; return v.f;
}
__device__ inline float bfhi(int p) {
    union { unsigned u; float f; } v; v.u = (unsigned)p & 0xffff0000u; return v.f;
}
__device__ inline float bf2f(unsigned short s) {
    union { unsigned u; float f; } v; v.u = (unsigned)s << 16; return v.f;
}
__device__ inline int aload(const int* p) {
    return __hip_atomic_load(p, __ATOMIC_RELAXED, __HIP_MEMORY_SCOPE_AGENT);
}
__device__ inline float aloadf(const float* p) {
    return __hip_atomic_load(p, __ATOMIC_RELAXED, __HIP_MEMORY_SCOPE_AGENT);
}

// ---------------- weight prep + workspace zeroing (replaces memset) ----------------

__global__ __launch_bounds__(256) void k_wprep(const float* __restrict__ W0,
                                               const float* __restrict__ W1,
                                               const float* __restrict__ W2,
                                               const float* __restrict__ as0,
                                               const float* __restrict__ ad0,
                                               const float* __restrict__ as1,
                                               const float* __restrict__ ad1,
                                               const float* __restrict__ as2,
                                               const float* __restrict__ ad2,
                                               short* __restrict__ Wt0,
                                               short* __restrict__ Wt1,
                                               short* __restrict__ Wt2,
                                               float* __restrict__ part,
                                               int* __restrict__ bucket_cnt,
                                               int* __restrict__ done) {
    int i = blockIdx.x * blockDim.x + threadIdx.x;
    if (i < 64 * 256) part[i] = 0.f;
    if (i < 1024) bucket_cnt[i] = 0;
    if (i < 4) done[i] = 0;

    if (i < 128 * 128) {
        int n = i >> 7, k = i & 127;
        Wt0[n * 128 + k] = f2bf(W0[k * 128 + n]);
        Wt1[n * 128 + k] = f2bf(W1[k * 128 + n]);
    } else if (i < 128 * 128 + 64 * 128) {
        int j = i - 128 * 128;
        int n = j >> 7, k = j & 127;
        Wt2[n * 128 + k] = f2bf(W2[k * 64 + n]);
    } else if (i < 128 * 128 + 64 * 128 + 128 * 8) {
        int j = i - (128 * 128 + 64 * 128);
        int k = j >> 3, h = j & 7;
        float s0 = 0.f, d0 = 0.f, s1 = 0.f, d1 = 0.f;
        #pragma unroll
        for (int d = 0; d < 16; d++) {
            float w0 = W0[k * 128 + h * 16 + d];
            float w1 = W1[k * 128 + h * 16 + d];
            s0 += w0 * as0[h * 16 + d];
            d0 += w0 * ad0[h * 16 + d];
            s1 += w1 * as1[h * 16 + d];
            d1 += w1 * ad1[h * 16 + d];
        }
        Wt0[(128 + h) * 128 + k] = f2bf(s0);
        Wt0[(136 + h) * 128 + k] = f2bf(d0);
        Wt1[(128 + h) * 128 + k] = f2bf(s1);
        Wt1[(136 + h) * 128 + k] = f2bf(d1);
    } else if (i < 128 * 128 + 64 * 128 + 128 * 8 + 128) {
        int k = i - (128 * 128 + 64 * 128 + 128 * 8);
        float s = 0.f, d = 0.f;
        #pragma unroll
        for (int dd = 0; dd < 64; dd++) {
            float w = W2[k * 64 + dd];
            s += w * as2[dd];
            d += w * ad2[dd];
        }
        Wt2[64 * 128 + k] = f2bf(s);
        Wt2[65 * 128 + k] = f2bf(d);
        #pragma unroll
        for (int r = 66; r < 80; r++) Wt2[r * 128 + k] = 0;
    }
}

// ---------------- bucket histogram + fused last-block scan -> ebase/bcursor -----------
// Buckets of 128 dst nodes; nb = ceil(N/128) must be <= 1024 (N <= 131072).

constexpr int EPT = 16;

__global__ __launch_bounds__(256) void k_binc(const int* __restrict__ dstE, int E, int nb,
                                              int* __restrict__ bucket_cnt,
                                              int Etot, int N,
                                              int* __restrict__ ebase,
                                              int* __restrict__ bcursor,
                                              int* __restrict__ rowptr,
                                              int* __restrict__ done) {
    __shared__ int cnt[1024];
    __shared__ int ws[4];
    __shared__ int lastflag;
    for (int b = threadIdx.x; b < nb; b += 256) cnt[b] = 0;
    __syncthreads();
    int i0 = blockIdx.x * (256 * EPT) + threadIdx.x;
    #pragma unroll
    for (int k = 0; k < EPT; k++) {
        int i = i0 + k * 256;
        if (i < E) atomicAdd(&cnt[dstE[i] >> 7], 1);
    }
    __syncthreads();
    for (int b = threadIdx.x; b < nb; b += 256) {
        int c = cnt[b];
        if (c) atomicAdd(&bucket_cnt[b], c);
    }
    // last-block scan
    __threadfence();
    __syncthreads();
    if (threadIdx.x == 0)
        lastflag = (atomicAdd(done, 1) == (int)gridDim.x - 1) ? 1 : 0;
    __syncthreads();
    if (!lastflag) return;

    int t = threadIdx.x;
    int c4[4];
    int s = 0;
    #pragma unroll
    for (int i = 0; i < 4; i++) {
        int b = t * 4 + i;
        c4[i] = (b < nb) ? aload(&bucket_cnt[b]) : 0;
        s += c4[i];
    }
    int lane = t & 63, wid = t >> 6;
    int x = s;
    #pragma unroll
    for (int off = 1; off < 64; off <<= 1) {
        int y = __shfl_up(x, off, 64);
        if (lane >= off) x += y;
    }
    if (lane == 63) ws[wid] = x;
    __syncthreads();
    int add = 0;
    for (int i = 0; i < wid; i++) add += ws[i];
    int excl = x - s + add;
    #pragma unroll
    for (int i = 0; i < 4; i++) {
        int b = t * 4 + i;
        if (b < nb) { ebase[b] = excl; bcursor[b] = excl; }
        excl += c4[i];
    }
    if (t == 0) { ebase[nb] = E; rowptr[N] = Etot; }
}

// ---------------- binned edge scatter: block-local multisplit ----------------

__global__ __launch_bounds__(256) void k_bin(const int* __restrict__ srcE,
                                             const int* __restrict__ dstE, int E, int nb,
                                             int* __restrict__ bcursor,
                                             int2* __restrict__ ebin) {
    __shared__ int cnt[1024];
    __shared__ int base[1024];
    for (int b = threadIdx.x; b < nb; b += 256) cnt[b] = 0;
    __syncthreads();
    int i0 = blockIdx.x * (256 * EPT) + threadIdx.x;
    int rb[EPT];
    #pragma unroll
    for (int k = 0; k < EPT; k++) {
        int i = i0 + k * 256;
        if (i < E) {
            int b = dstE[i] >> 7;
            rb[k] = (atomicAdd(&cnt[b], 1) << 10) | b;   // rank(12b) | bucket(10b)
        } else {
            rb[k] = -1;
        }
    }
    __syncthreads();
    for (int b = threadIdx.x; b < nb; b += 256) {
        int c = cnt[b];
        base[b] = c ? atomicAdd(&bcursor[b], c) : 0;
    }
    __syncthreads();
    #pragma unroll
    for (int k = 0; k < EPT; k++) {
        int i = i0 + k * 256;
        if (i < E) {
            int v = rb[k];
            int b = v & 1023;
            int r = v >> 10;
            ebin[base[b] + r] = make_int2(srcE[i], dstE[i]);   // re-read: L1/L2 hot
        }
    }
}

// ---------------- CSR fill: per bucket; LDS degree count + scan -> rowptr + col -------

__global__ __launch_bounds__(256) void k_cfill2(const int* __restrict__ ebase,
                                                const int2* __restrict__ ebin,
                                                int* __restrict__ rowptr,
                                                int* __restrict__ col, int N) {
    const int b = blockIdx.x;
    const int n0 = b << 7;
    int nn = N - n0; if (nn > 128) nn = 128;
    __shared__ int cnt[128];
    __shared__ int wtot[2];
    const int t = threadIdx.x;
    if (t < 128) cnt[t] = 0;
    __syncthreads();
    const int e0 = ebase[b];
    const int e1 = ebase[b + 1];
    for (int i = e0 + t; i < e1; i += 256) {
        atomicAdd(&cnt[ebin[i].y & 127], 1);
    }
    __syncthreads();
    int v = (t < 128) ? cnt[t] : 0;
    int lane = t & 63;
    int x = v;
    #pragma unroll
    for (int off = 1; off < 64; off <<= 1) {
        int y = __shfl_up(x, off, 64);
        if (lane >= off) x += y;
    }
    if (t < 128 && lane == 63) wtot[t >> 6] = x;
    __syncthreads();
    int excl = x - v + ((t >= 64 && t < 128) ? wtot[0] : 0);
    if (t < nn) {
        int rp = e0 + n0 + t + excl;
        rowptr[n0 + t] = rp;
        col[rp] = n0 + t;            // self loop in first slot of its row
        cnt[t] = rp + 1;             // reuse cnt[] as per-node cursor
    }
    __syncthreads();
    for (int i = e0 + t; i < e1; i += 256) {
        int2 e = ebin[i];
        int p = atomicAdd(&cnt[e.y & 127], 1);
        col[p] = e.x;
    }
}

// ---------------- MFMA bf16 GEMM + fused BN-apply; logits via augmented columns -------
// HASBN: X is bf16 'agg'; y = relu(X*scale+shift)+Xres. RESBF16: Xres is bf16.
// WRITEX: store y (bf16) to Xout.

template <int DOUT, bool HASBN, bool RESBF16, bool WRITEX>
__global__ __launch_bounds__(256) void k_gemm(const void* __restrict__ Xv,
                                              const short* __restrict__ Wt,
                                              short* __restrict__ Hout,
                                              const float2* __restrict__ ss,
                                              const void* __restrict__ Xresv,
                                              short* __restrict__ Xout,
                                              float* __restrict__ als,
                                              float* __restrict__ ald, int Nrows) {
    constexpr int KP = 136;
    constexpr int CT = DOUT / 16;
    constexpr int CTT = CT + 1;
    __shared__ __align__(16) short Xs[128 * KP];
    __shared__ __align__(16) short Ws[(DOUT + 16) * KP];

    const int tid = threadIdx.x;
    const int row0 = blockIdx.x * 128;

    {
        int c4 = tid & 31;
        int r0 = tid >> 5;
        float2 ssv[4];
        if (HASBN) {
            #pragma unroll
            for (int j = 0; j < 4; j++) ssv[j] = ss[c4 * 4 + j];
        }
        #pragma unroll
        for (int p = 0; p < 16; p++) {
            int r = r0 + p * 8;
            int grow = row0 + r;
            float vp[4] = {0.f, 0.f, 0.f, 0.f};
            if (grow < Nrows) {
                if (HASBN) {
                    short4 xb = *(const short4*)&((const short*)Xv)[(size_t)grow * 128 + c4 * 4];
                    vp[0] = bf2f((unsigned short)xb.x);
                    vp[1] = bf2f((unsigned short)xb.y);
                    vp[2] = bf2f((unsigned short)xb.z);
                    vp[3] = bf2f((unsigned short)xb.w);
                    float xr[4];
                    if (RESBF16) {
                        short4 rb = *(const short4*)&((const short*)Xresv)[(size_t)grow * 128 + c4 * 4];
                        xr[0] = bf2f((unsigned short)rb.x);
                        xr[1] = bf2f((unsigned short)rb.y);
                        xr[2] = bf2f((unsigned short)rb.z);
                        xr[3] = bf2f((unsigned short)rb.w);
                    } else {
                        float4 rf = *(const float4*)&((const float*)Xresv)[(size_t)grow * 128 + c4 * 4];
                        xr[0] = rf.x; xr[1] = rf.y; xr[2] = rf.z; xr[3] = rf.w;
                    }
                    #pragma unroll
                    for (int j = 0; j < 4; j++)
                        vp[j] = fmaxf(vp[j] * ssv[j].x + ssv[j].y, 0.f) + xr[j];
                } else {
                    float4 v = *(const float4*)&((const float*)Xv)[(size_t)grow * 128 + c4 * 4];
                    vp[0] = v.x; vp[1] = v.y; vp[2] = v.z; vp[3] = v.w;
                }
            }
            short4 b;
            b.x = f2bf(vp[0]); b.y = f2bf(vp[1]); b.z = f2bf(vp[2]); b.w = f2bf(vp[3]);
            if (WRITEX && grow < Nrows)
                *(short4*)&Xout[(size_t)grow * 128 + c4 * 4] = b;
            *(short4*)&Xs[r * KP + c4 * 4] = b;
        }
    }
    {
        constexpr int UNITS = (DOUT + 16) * 16;
        #pragma unroll
        for (int p = 0; p < UNITS / 256; p++) {
            int u = tid + p * 256;
            int n = u >> 4;
            int kc = (u & 15) * 8;
            bf16x8 v = *(const bf16x8*)&Wt[n * 128 + kc];
            *(bf16x8*)&Ws[n * KP + kc] = v;
        }
    }
    __syncthreads();

    const int lane = tid & 63;
    const int wv = tid >> 6;
    const int m0 = wv * 32;
    const int ln = lane & 15;
    const int quad = lane >> 4;

    floatx4 acc[2][CTT];
    #pragma unroll
    for (int mt = 0; mt < 2; mt++)
        #pragma unroll
        for (int ct = 0; ct < CTT; ct++) acc[mt][ct] = (floatx4){0.f, 0.f, 0.f, 0.f};

    #pragma unroll
    for (int ks = 0; ks < 4; ks++) {
        int ko = ks * 32 + quad * 8;
        bf16x8 a0 = *(const bf16x8*)&Xs[(m0 + ln) * KP + ko];
        bf16x8 a1 = *(const bf16x8*)&Xs[(m0 + 16 + ln) * KP + ko];
        #pragma unroll
        for (int ct = 0; ct < CTT; ct++) {
            bf16x8 b = *(const bf16x8*)&Ws[(ct * 16 + ln) * KP + ko];
            acc[0][ct] = __builtin_amdgcn_mfma_f32_16x16x32_bf16(a0, b, acc[0][ct], 0, 0, 0);
            acc[1][ct] = __builtin_amdgcn_mfma_f32_16x16x32_bf16(a1, b, acc[1][ct], 0, 0, 0);
        }
    }

    #pragma unroll
    for (int mt = 0; mt < 2; mt++) {
        #pragma unroll
        for (int r = 0; r < 4; r++) {
            int grow = row0 + m0 + mt * 16 + quad * 4 + r;
            if (grow < Nrows) {
                #pragma unroll
                for (int ct = 0; ct < CT; ct++)
                    Hout[(size_t)grow * DOUT + ct * 16 + ln] = f2bf(acc[mt][ct][r]);
                float aug = acc[mt][CT][r];
                if (DOUT == 128) {
                    if (ln < 8) als[grow * 8 + ln] = aug;
                    else        ald[grow * 8 + (ln - 8)] = aug;
                } else {
                    if (ln == 0) als[grow] = aug;
                    else if (ln == 1) ald[grow] = aug;
                }
            }
        }
    }
}

// ---------------- aggregate: half-wave per node, int4 row loads, 2 edge subgroups -----
// + fused last-block BN reduce (part -> ss, re-zero part).

__global__ __launch_bounds__(256) void k_agg(const int* __restrict__ rowptr,
                                             const int* __restrict__ col,
                                             const short* __restrict__ Hb,
                                             const float* __restrict__ als,
                                             const float* __restrict__ ald,
                                             const float* __restrict__ bias,
                                             short* __restrict__ out,
                                             float* __restrict__ part, int N,
                                             const float* __restrict__ bng,
                                             const float* __restrict__ bnbt,
                                             float invN, float2* __restrict__ ss,
                                             int* __restrict__ done) {
    __shared__ float red[8][128];
    __shared__ int lastflag;
    const int wv = threadIdx.x >> 6;
    const int lane = threadIdx.x & 63;
    const int g = lane >> 5;          // node slot within wave
    const int f = lane & 31;
    const int g2 = f >> 4;            // edge subgroup
    const int q = f & 15;             // int4 slice -> feats 8q..8q+7
    const int h = q >> 1;             // head
    const int node = blockIdx.x * 8 + wv * 2 + g;
    const int4* H4 = (const int4*)Hb;

    int j = 0, deg = 0;
    float aldv = 0.f;
    if (node < N) {
        j = rowptr[node];
        deg = rowptr[node + 1] - j;
        aldv = ald[node * 8 + h];
    }
    float s = 0.f;
    float a[8] = {0.f, 0.f, 0.f, 0.f, 0.f, 0.f, 0.f, 0.f};

    int done_e = 0;
    while (__any(done_e < deg)) {
        int take = deg - done_e;
        if (take > 32) take = 32;
        if (take < 0) take = 0;
        int li = (f < take) ? f : (take - 1);
        if (li < 0) li = 0;
        int cbuf = col[j + done_e + li];      // lane f holds col[j+done+f] (clamped)
        for (int k = 0; __any(k < take); k += 4) {
            int e0 = k + g2, e1 = k + 2 + g2;
            int c0 = __shfl(cbuf, e0, 32);
            int c1 = __shfl(cbuf, e1, 32);
            float aw0 = als[c0 * 8 + h];
            float aw1 = als[c1 * 8 + h];
            int4 p0 = H4[c0 * 16 + q];
            int4 p1 = H4[c1 * 16 + q];
            float x0 = aw0 + aldv; x0 = LRELU(x0);
            float x1 = aw1 + aldv; x1 = LRELU(x1);
            float w0 = (e0 < take) ? __expf(x0) : 0.f;
            float w1 = (e1 < take) ? __expf(x1) : 0.f;
            s += w0;
            a[0] += w0 * bflo(p0.x); a[1] += w0 * bfhi(p0.x);
            a[2] += w0 * bflo(p0.y); a[3] += w0 * bfhi(p0.y);
            a[4] += w0 * bflo(p0.z); a[5] += w0 * bfhi(p0.z);
            a[6] += w0 * bflo(p0.w); a[7] += w0 * bfhi(p0.w);
            s += w1;
            a[0] += w1 * bflo(p1.x); a[1] += w1 * bfhi(p1.x);
            a[2] += w1 * bflo(p1.y); a[3] += w1 * bfhi(p1.y);
            a[4] += w1 * bflo(p1.z); a[5] += w1 * bfhi(p1.z);
            a[6] += w1 * bflo(p1.w); a[7] += w1 * bfhi(p1.w);
        }
        done_e += take;
    }

    // combine the two edge subgroups (lanes f and f^16 share slice q)
    s += __shfl_xor(s, 16, 32);
    #pragma unroll
    for (int i = 0; i < 8; i++) a[i] += __shfl_xor(a[i], 16, 32);

    float o[8];
    #pragma unroll
    for (int i = 0; i < 8; i++) o[i] = 0.f;
    if (node < N) {
        float4 bv0 = ((const float4*)bias)[2 * q];
        float4 bv1 = ((const float4*)bias)[2 * q + 1];
        float inv = 1.f / (s + 1e-16f);
        o[0] = a[0] * inv + bv0.x;
        o[1] = a[1] * inv + bv0.y;
        o[2] = a[2] * inv + bv0.z;
        o[3] = a[3] * inv + bv0.w;
        o[4] = a[4] * inv + bv1.x;
        o[5] = a[5] * inv + bv1.y;
        o[6] = a[6] * inv + bv1.z;
        o[7] = a[7] * inv + bv1.w;
        if (g2 == 0) {
            int4 pk;
            pk.x = (int)((unsigned short)f2bf(o[0]) | ((unsigned)(unsigned short)f2bf(o[1]) << 16));
            pk.y = (int)((unsigned short)f2bf(o[2]) | ((unsigned)(unsigned short)f2bf(o[3]) << 16));
            pk.z = (int)((unsigned short)f2bf(o[4]) | ((unsigned)(unsigned short)f2bf(o[5]) << 16));
            pk.w = (int)((unsigned short)f2bf(o[6]) | ((unsigned)(unsigned short)f2bf(o[7]) << 16));
            ((int4*)out)[(size_t)node * 16 + q] = pk;
        }
    }
    const int rrow = wv * 2 + g;
    // both subgroups hold identical o[]; split the 8 stores between them
    #pragma unroll
    for (int i = 0; i < 4; i++)
        red[rrow][8 * q + 4 * g2 + i] = o[4 * g2 + i];
    __syncthreads();
    if (threadIdx.x < 128) {
        int c = threadIdx.x;
        float s2 = 0.f, qq = 0.f;
        #pragma unroll
        for (int r = 0; r < 8; r++) {
            float v = red[r][c];
            s2 += v;
            qq += v * v;
        }
        float* slot = part + (blockIdx.x & 63) * 256;
        atomicAdd(&slot[c], s2);
        atomicAdd(&slot[128 + c], qq);
    }

    // ---- fused BN reduce: last block computes (scale, shift), re-zeroes part ----
    __threadfence();
    __syncthreads();
    if (threadIdx.x == 0)
        lastflag = (atomicAdd(done, 1) == (int)gridDim.x - 1) ? 1 : 0;
    __syncthreads();
    if (!lastflag) return;
    if (threadIdx.x < 128) {
        int c = threadIdx.x;
        float s2 = 0.f, qq = 0.f;
        #pragma unroll
        for (int k = 0; k < 64; k++) {
            s2 += aloadf(&part[k * 256 + c]);
            qq += aloadf(&part[k * 256 + 128 + c]);
        }
        #pragma unroll
        for (int k = 0; k < 64; k++) {
            part[k * 256 + c] = 0.f;
            part[k * 256 + 128 + c] = 0.f;
        }
        float mu = s2 * invN;
        float var = qq * invN - mu * mu;
        float scale = rsqrtf(var + 1e-5f) * bng[c];
        ss[c] = make_float2(scale, bnbt[c] - mu * scale);
    }
}

// ---------------- layer-2: half-wave per node, int4 loads, 4 edge subgroups + LN ------

__global__ __launch_bounds__(256) void k_agg2ln(const int* __restrict__ rowptr,
                                                const int* __restrict__ col,
                                                const short* __restrict__ Hb2,
                                                const float* __restrict__ als,
                                                const float* __restrict__ ald,
                                                const float* __restrict__ b2,
                                                const float* __restrict__ lng,
                                                const float* __restrict__ lnb,
                                                float* __restrict__ out, int N) {
    const int wv = threadIdx.x >> 6;
    const int lane = threadIdx.x & 63;
    const int g = lane >> 5;
    const int f = lane & 31;
    const int g4 = f >> 3;            // edge subgroup (0..3)
    const int q = f & 7;              // int4 slice -> feats 8q..8q+7
    const int node = blockIdx.x * 8 + wv * 2 + g;
    const int4* H4 = (const int4*)Hb2;
    const bool vn = node < N;

    int j = 0, deg = 0;
    float aldv = 0.f;
    if (vn) {
        j = rowptr[node];
        deg = rowptr[node + 1] - j;
        aldv = ald[node];
    }
    float s = 0.f;
    float a[8] = {0.f, 0.f, 0.f, 0.f, 0.f, 0.f, 0.f, 0.f};

    int done_e = 0;
    while (__any(done_e < deg)) {
        int take = deg - done_e;
        if (take > 32) take = 32;
        if (take < 0) take = 0;
        int li = (f < take) ? f : (take - 1);
        if (li < 0) li = 0;
        int cbuf = col[j + done_e + li];
        for (int k = 0; __any(k < take); k += 8) {
            int e0 = k + g4, e1 = k + 4 + g4;
            int c0 = __shfl(cbuf, e0, 32);
            int c1 = __shfl(cbuf, e1, 32);
            float aw0 = als[c0];
            float aw1 = als[c1];
            int4 p0 = H4[c0 * 8 + q];
            int4 p1 = H4[c1 * 8 + q];
            float x0 = aw0 + aldv; x0 = LRELU(x0);
            float x1 = aw1 + aldv; x1 = LRELU(x1);
            float w0 = (e0 < take) ? __expf(x0) : 0.f;
            float w1 = (e1 < take) ? __expf(x1) : 0.f;
            s += w0;
            a[0] += w0 * bflo(p0.x); a[1] += w0 * bfhi(p0.x);
            a[2] += w0 * bflo(p0.y); a[3] += w0 * bfhi(p0.y);
            a[4] += w0 * bflo(p0.z); a[5] += w0 * bfhi(p0.z);
            a[6] += w0 * bflo(p0.w); a[7] += w0 * bfhi(p0.w);
            s += w1;
            a[0] += w1 * bflo(p1.x); a[1] += w1 * bfhi(p1.x);
            a[2] += w1 * bflo(p1.y); a[3] += w1 * bfhi(p1.y);
            a[4] += w1 * bflo(p1.z); a[5] += w1 * bfhi(p1.z);
            a[6] += w1 * bflo(p1.w); a[7] += w1 * bfhi(p1.w);
        }
        done_e += take;
    }

    // combine the four edge subgroups (same q across g4)
    s += __shfl_xor(s, 8, 32);
    s += __shfl_xor(s, 16, 32);
    #pragma unroll
    for (int i = 0; i < 8; i++) {
        a[i] += __shfl_xor(a[i], 8, 32);
        a[i] += __shfl_xor(a[i], 16, 32);
    }

    if (!vn) return;
    float inv = 1.f / (s + 1e-16f);
    float4 bv0 = ((const float4*)b2)[2 * q];
    float4 bv1 = ((const float4*)b2)[2 * q + 1];
    float v[8];
    v[0] = a[0] * inv + bv0.x;
    v[1] = a[1] * inv + bv0.y;
    v[2] = a[2] * inv + bv0.z;
    v[3] = a[3] * inv + bv0.w;
    v[4] = a[4] * inv + bv1.x;
    v[5] = a[5] * inv + bv1.y;
    v[6] = a[6] * inv + bv1.z;
    v[7] = a[7] * inv + bv1.w;
    float su = 0.f, sq = 0.f;
    #pragma unroll
    for (int i = 0; i < 8; i++) { su += v[i]; sq += v[i] * v[i]; }
    // reduce across q (bits 0..2 of f)
    su += __shfl_xor(su, 1, 32); sq += __shfl_xor(sq, 1, 32);
    su += __shfl_xor(su, 2, 32); sq += __shfl_xor(sq, 2, 32);
    su += __shfl_xor(su, 4, 32); sq += __shfl_xor(sq, 4, 32);
    float mu = su * (1.f / 64.f);
    float var = sq * (1.f / 64.f) - mu * mu;
    float r = rsqrtf(var + 1e-5f);
    if (g4 == 0) {
        float4 lg0 = ((const float4*)lng)[2 * q];
        float4 lg1 = ((const float4*)lng)[2 * q + 1];
        float4 lb0 = ((const float4*)lnb)[2 * q];
        float4 lb1 = ((const float4*)lnb)[2 * q + 1];
        float4 o0, o1;
        o0.x = (v[0] - mu) * r * lg0.x + lb0.x;
        o0.y = (v[1] - mu) * r * lg0.y + lb0.y;
        o0.z = (v[2] - mu) * r * lg0.z + lb0.z;
        o0.w = (v[3] - mu) * r * lg0.w + lb0.w;
        o1.x = (v[4] - mu) * r * lg1.x + lb1.x;
        o1.y = (v[5] - mu) * r * lg1.y + lb1.y;
        o1.z = (v[6] - mu) * r * lg1.z + lb1.z;
        o1.w = (v[7] - mu) * r * lg1.w + lb1.w;
        ((float4*)out)[(size_t)node * 16 + 2 * q] = o0;
        ((float4*)out)[(size_t)node * 16 + 2 * q + 1] = o1;
    }
}

// ---------------- launch ----------------

extern "C" void kernel_launch(void* const* d_in, const int* in_sizes, int n_in,
                              void* d_out, int out_size, void* d_ws, size_t ws_size,
                              hipStream_t stream) {
    const float* x   = (const float*)d_in[0];
    const int*   ei  = (const int*)d_in[1];
    const float* W0  = (const float*)d_in[2];
    const float* as0 = (const float*)d_in[3];
    const float* ad0 = (const float*)d_in[4];
    const float* b0  = (const float*)d_in[5];
    const float* g0  = (const float*)d_in[6];
    const float* bt0 = (const float*)d_in[7];
    const float* W1  = (const float*)d_in[8];
    const float* as1 = (const float*)d_in[9];
    const float* ad1 = (const float*)d_in[10];
    const float* b1  = (const float*)d_in[11];
    const float* g1  = (const float*)d_in[12];
    const float* bt1 = (const float*)d_in[13];
    const float* W2  = (const float*)d_in[14];
    const float* as2 = (const float*)d_in[15];
    const float* ad2 = (const float*)d_in[16];
    const float* b2  = (const float*)d_in[17];
    const float* lng = (const float*)d_in[18];
    const float* lnb = (const float*)d_in[19];

    const int N = in_sizes[0] / 128;
    const int E = in_sizes[1] / 2;
    const int Etot = E + N;
    const int nb = (N + 127) >> 7;     // buckets of 128 nodes (requires nb <= 1024)

    char* p = (char*)d_ws;
    auto carve = [&](size_t bytes) {
        void* q = (void*)p;
        p += (bytes + 255) & ~(size_t)255;
        return q;
    };
    short* Hb     = (short*)carve((size_t)N * 128 * 2);
    short* aggb   = (short*)carve((size_t)N * 128 * 2);
    short* x1b    = (short*)carve((size_t)N * 128 * 2);
    float* als    = (float*)carve((size_t)N * 8 * 4);
    float* ald    = (float*)carve((size_t)N * 8 * 4);
    int*   rowptr = (int*)carve((size_t)(N + 1) * 4);
    int*   bucket_cnt = (int*)carve(1024 * 4);
    float* part   = (float*)carve(64 * 256 * 4);
    int*   col    = (int*)carve((size_t)(Etot + 64) * 4);
    int2*  ebin   = (int2*)carve((size_t)E * 8);
    int*   ebase  = (int*)carve(1028 * 4);
    int*   bcursor= (int*)carve(1024 * 4);
    float2* ss    = (float2*)carve(128 * 8);
    short* Wt0    = (short*)carve(144 * 128 * 2);
    short* Wt1    = (short*)carve(144 * 128 * 2);
    short* Wt2    = (short*)carve(80 * 128 * 2);
    int*   done   = (int*)carve(4 * 4);

    const float invN = 1.f / (float)N;
    const int bb = (E + 256 * EPT - 1) / (256 * EPT);
    const int wpb = (128 * 128 + 64 * 128 + 128 * 8 + 128 + 255) / 256;

    k_wprep<<<wpb, 256, 0, stream>>>(W0, W1, W2, as0, ad0, as1, ad1, as2, ad2,
                                     Wt0, Wt1, Wt2, part, bucket_cnt, done);
    k_binc<<<bb, 256, 0, stream>>>(ei + E, E, nb, bucket_cnt, Etot, N,
                                   ebase, bcursor, rowptr, done + 0);
    k_bin<<<bb, 256, 0, stream>>>(ei, ei + E, E, nb, bcursor, ebin);
    k_cfill2<<<nb, 256, 0, stream>>>(ebase, ebin, rowptr, col, N);

    const int gb = (N + 127) / 128;
    const int ab = (N + 7) / 8;

    // ---- layer 0 ----
    k_gemm<128, false, false, false><<<gb, 256, 0, stream>>>(x, Wt0, Hb, nullptr, nullptr,
                                                             nullptr, als, ald, N);
    k_agg<<<ab, 256, 0, stream>>>(rowptr, col, Hb, als, ald, b0, aggb, part, N,
                                  g0, bt0, invN, ss, done + 1);

    // ---- layer 1 (BN-apply fused into GEMM staging; agg/x1 bf16) ----
    k_gemm<128, true, false, true><<<gb, 256, 0, stream>>>(aggb, Wt1, Hb, ss, x, x1b,
                                                           als, ald, N);
    k_agg<<<ab, 256, 0, stream>>>(rowptr, col, Hb, als, ald, b1, aggb, part, N,
                                  g1, bt1, invN, ss, done + 2);

    // ---- layer 2 (BN-apply fused; bf16 residual; x2 never materialized) ----
    k_gemm<64, true, true, false><<<gb, 256, 0, stream>>>(aggb, Wt2, Hb, ss, x1b, nullptr,
                                                          als, ald, N);
    k_agg2ln<<<ab, 256, 0, stream>>>(rowptr, col, Hb, als, ald, b2, lng, lnb,
                                     (float*)d_out, N);
}

// Round 10
// 363.947 us; speedup vs baseline: 7.6949x; 7.6949x over previous
//
#include <hip/hip_runtime.h>
#include <hip/hip_bf16.h>

#define LRELU(e) ((e) > 0.f ? (e) : 0.2f * (e))

typedef __attribute__((ext_vector_type(8))) short bf16x8;
typedef __attribute__((ext_vector_type(4))) float floatx4;

__device__ inline short f2bf(float f) {
    union { float f; unsigned u; } v; v.f = f;
    unsigned r = v.u + 0x7fffu + ((v.u >> 16) & 1u);
    return (short)(r >> 16);
}
__device__ inline float bflo(int p) {
    union { unsigned u; float f; } v; v.u = (unsigned)p << 16; return v.f;
}
__device__ inline float bfhi(int p) {
    union { unsigned u; float f; } v; v.u = (unsigned)p & 0xffff0000u; return v.f;
}
__device__ inline float bf2f(unsigned short s) {
    union { unsigned u; float f; } v; v.u = (unsigned)s << 16; return v.f;
}

// ---------------- weight prep + workspace zeroing (replaces memset dispatch) ----------

__global__ __launch_bounds__(256) void k_wprep(const float* __restrict__ W0,
                                               const float* __restrict__ W1,
                                               const float* __restrict__ W2,
                                               const float* __restrict__ as0,
                                               const float* __restrict__ ad0,
                                               const float* __restrict__ as1,
                                               const float* __restrict__ ad1,
                                               const float* __restrict__ as2,
                                               const float* __restrict__ ad2,
                                               short* __restrict__ Wt0,
                                               short* __restrict__ Wt1,
                                               short* __restrict__ Wt2,
                                               float* __restrict__ part,
                                               int* __restrict__ bucket_cnt) {
    int i = blockIdx.x * blockDim.x + threadIdx.x;
    if (i < 64 * 256) part[i] = 0.f;
    if (i < 1024) bucket_cnt[i] = 0;

    if (i < 128 * 128) {
        int n = i >> 7, k = i & 127;
        Wt0[n * 128 + k] = f2bf(W0[k * 128 + n]);
        Wt1[n * 128 + k] = f2bf(W1[k * 128 + n]);
    } else if (i < 128 * 128 + 64 * 128) {
        int j = i - 128 * 128;
        int n = j >> 7, k = j & 127;
        Wt2[n * 128 + k] = f2bf(W2[k * 64 + n]);
    } else if (i < 128 * 128 + 64 * 128 + 128 * 8) {
        int j = i - (128 * 128 + 64 * 128);
        int k = j >> 3, h = j & 7;
        float s0 = 0.f, d0 = 0.f, s1 = 0.f, d1 = 0.f;
        #pragma unroll
        for (int d = 0; d < 16; d++) {
            float w0 = W0[k * 128 + h * 16 + d];
            float w1 = W1[k * 128 + h * 16 + d];
            s0 += w0 * as0[h * 16 + d];
            d0 += w0 * ad0[h * 16 + d];
            s1 += w1 * as1[h * 16 + d];
            d1 += w1 * ad1[h * 16 + d];
        }
        Wt0[(128 + h) * 128 + k] = f2bf(s0);
        Wt0[(136 + h) * 128 + k] = f2bf(d0);
        Wt1[(128 + h) * 128 + k] = f2bf(s1);
        Wt1[(136 + h) * 128 + k] = f2bf(d1);
    } else if (i < 128 * 128 + 64 * 128 + 128 * 8 + 128) {
        int k = i - (128 * 128 + 64 * 128 + 128 * 8);
        float s = 0.f, d = 0.f;
        #pragma unroll
        for (int dd = 0; dd < 64; dd++) {
            float w = W2[k * 64 + dd];
            s += w * as2[dd];
            d += w * ad2[dd];
        }
        Wt2[64 * 128 + k] = f2bf(s);
        Wt2[65 * 128 + k] = f2bf(d);
        #pragma unroll
        for (int r = 66; r < 80; r++) Wt2[r * 128 + k] = 0;
    }
}

// ---------------- bucket histogram (LDS) -> global bucket counts ----------------
// Buckets of 128 dst nodes; nb = ceil(N/128) must be <= 1024 (N <= 131072).

constexpr int EPT = 16;

__global__ __launch_bounds__(256) void k_binc(const int* __restrict__ dstE, int E, int nb,
                                              int* __restrict__ bucket_cnt) {
    __shared__ int cnt[1024];
    for (int b = threadIdx.x; b < nb; b += 256) cnt[b] = 0;
    __syncthreads();
    int i0 = blockIdx.x * (256 * EPT) + threadIdx.x;
    #pragma unroll
    for (int k = 0; k < EPT; k++) {
        int i = i0 + k * 256;
        if (i < E) atomicAdd(&cnt[dstE[i] >> 7], 1);
    }
    __syncthreads();
    for (int b = threadIdx.x; b < nb; b += 256) {
        int c = cnt[b];
        if (c) atomicAdd(&bucket_cnt[b], c);
    }
}

// ---------------- scan bucket counts -> ebase / bcursor (one small block) -------------

__global__ __launch_bounds__(256) void k_scanb(const int* __restrict__ bucket_cnt, int nb,
                                               int E, int Etot, int N,
                                               int* __restrict__ ebase,
                                               int* __restrict__ bcursor,
                                               int* __restrict__ rowptr) {
    int t = threadIdx.x;
    int c[4];
    int s = 0;
    #pragma unroll
    for (int i = 0; i < 4; i++) {
        int b = t * 4 + i;
        c[i] = (b < nb) ? bucket_cnt[b] : 0;
        s += c[i];
    }
    int lane = t & 63, wid = t >> 6;
    int x = s;
    #pragma unroll
    for (int off = 1; off < 64; off <<= 1) {
        int y = __shfl_up(x, off, 64);
        if (lane >= off) x += y;
    }
    __shared__ int ws[4];
    if (lane == 63) ws[wid] = x;
    __syncthreads();
    int add = 0;
    for (int i = 0; i < wid; i++) add += ws[i];
    int excl = x - s + add;
    #pragma unroll
    for (int i = 0; i < 4; i++) {
        int b = t * 4 + i;
        if (b < nb) { ebase[b] = excl; bcursor[b] = excl; }
        excl += c[i];
    }
    if (t == 0) { ebase[nb] = E; rowptr[N] = Etot; }
}

// ---------------- binned edge scatter: block-local multisplit ----------------

__global__ __launch_bounds__(256) void k_bin(const int* __restrict__ srcE,
                                             const int* __restrict__ dstE, int E, int nb,
                                             int* __restrict__ bcursor,
                                             int2* __restrict__ ebin) {
    __shared__ int cnt[1024];
    __shared__ int base[1024];
    for (int b = threadIdx.x; b < nb; b += 256) cnt[b] = 0;
    __syncthreads();
    int i0 = blockIdx.x * (256 * EPT) + threadIdx.x;
    int rb[EPT];
    #pragma unroll
    for (int k = 0; k < EPT; k++) {
        int i = i0 + k * 256;
        if (i < E) {
            int b = dstE[i] >> 7;
            rb[k] = (atomicAdd(&cnt[b], 1) << 10) | b;   // rank(12b) | bucket(10b)
        } else {
            rb[k] = -1;
        }
    }
    __syncthreads();
    for (int b = threadIdx.x; b < nb; b += 256) {
        int c = cnt[b];
        base[b] = c ? atomicAdd(&bcursor[b], c) : 0;
    }
    __syncthreads();
    #pragma unroll
    for (int k = 0; k < EPT; k++) {
        int i = i0 + k * 256;
        if (i < E) {
            int v = rb[k];
            int b = v & 1023;
            int r = v >> 10;
            ebin[base[b] + r] = make_int2(srcE[i], dstE[i]);   // re-read: L1/L2 hot
        }
    }
}

// ---------------- CSR fill: per bucket; LDS degree count + scan -> rowptr + col -------

__global__ __launch_bounds__(256) void k_cfill2(const int* __restrict__ ebase,
                                                const int2* __restrict__ ebin,
                                                int* __restrict__ rowptr,
                                                int* __restrict__ col, int N) {
    const int b = blockIdx.x;
    const int n0 = b << 7;
    int nn = N - n0; if (nn > 128) nn = 128;
    __shared__ int cnt[128];
    __shared__ int wtot[2];
    const int t = threadIdx.x;
    if (t < 128) cnt[t] = 0;
    __syncthreads();
    const int e0 = ebase[b];
    const int e1 = ebase[b + 1];
    for (int i = e0 + t; i < e1; i += 256) {
        atomicAdd(&cnt[ebin[i].y & 127], 1);
    }
    __syncthreads();
    int v = (t < 128) ? cnt[t] : 0;
    int lane = t & 63;
    int x = v;
    #pragma unroll
    for (int off = 1; off < 64; off <<= 1) {
        int y = __shfl_up(x, off, 64);
        if (lane >= off) x += y;
    }
    if (t < 128 && lane == 63) wtot[t >> 6] = x;
    __syncthreads();
    int excl = x - v + ((t >= 64 && t < 128) ? wtot[0] : 0);
    if (t < nn) {
        int rp = e0 + n0 + t + excl;
        rowptr[n0 + t] = rp;
        col[rp] = n0 + t;            // self loop in first slot of its row
        cnt[t] = rp + 1;             // reuse cnt[] as per-node cursor
    }
    __syncthreads();
    for (int i = e0 + t; i < e1; i += 256) {
        int2 e = ebin[i];
        int p = atomicAdd(&cnt[e.y & 127], 1);
        col[p] = e.x;
    }
}

// ---------------- MFMA bf16 GEMM + fused BN-apply; logits via augmented columns -------
// HASBN: X is bf16 'agg'; y = relu(X*scale+shift)+Xres. RESBF16: Xres is bf16.
// WRITEX: store y (bf16) to Xout.

template <int DOUT, bool HASBN, bool RESBF16, bool WRITEX>
__global__ __launch_bounds__(256) void k_gemm(const void* __restrict__ Xv,
                                              const short* __restrict__ Wt,
                                              short* __restrict__ Hout,
                                              const float2* __restrict__ ss,
                                              const void* __restrict__ Xresv,
                                              short* __restrict__ Xout,
                                              float* __restrict__ als,
                                              float* __restrict__ ald, int Nrows) {
    constexpr int KP = 136;
    constexpr int CT = DOUT / 16;
    constexpr int CTT = CT + 1;
    __shared__ __align__(16) short Xs[128 * KP];
    __shared__ __align__(16) short Ws[(DOUT + 16) * KP];

    const int tid = threadIdx.x;
    const int row0 = blockIdx.x * 128;

    {
        int c4 = tid & 31;
        int r0 = tid >> 5;
        float2 ssv[4];
        if (HASBN) {
            #pragma unroll
            for (int j = 0; j < 4; j++) ssv[j] = ss[c4 * 4 + j];
        }
        #pragma unroll
        for (int p = 0; p < 16; p++) {
            int r = r0 + p * 8;
            int grow = row0 + r;
            float vp[4] = {0.f, 0.f, 0.f, 0.f};
            if (grow < Nrows) {
                if (HASBN) {
                    short4 xb = *(const short4*)&((const short*)Xv)[(size_t)grow * 128 + c4 * 4];
                    vp[0] = bf2f((unsigned short)xb.x);
                    vp[1] = bf2f((unsigned short)xb.y);
                    vp[2] = bf2f((unsigned short)xb.z);
                    vp[3] = bf2f((unsigned short)xb.w);
                    float xr[4];
                    if (RESBF16) {
                        short4 rb = *(const short4*)&((const short*)Xresv)[(size_t)grow * 128 + c4 * 4];
                        xr[0] = bf2f((unsigned short)rb.x);
                        xr[1] = bf2f((unsigned short)rb.y);
                        xr[2] = bf2f((unsigned short)rb.z);
                        xr[3] = bf2f((unsigned short)rb.w);
                    } else {
                        float4 rf = *(const float4*)&((const float*)Xresv)[(size_t)grow * 128 + c4 * 4];
                        xr[0] = rf.x; xr[1] = rf.y; xr[2] = rf.z; xr[3] = rf.w;
                    }
                    #pragma unroll
                    for (int j = 0; j < 4; j++)
                        vp[j] = fmaxf(vp[j] * ssv[j].x + ssv[j].y, 0.f) + xr[j];
                } else {
                    float4 v = *(const float4*)&((const float*)Xv)[(size_t)grow * 128 + c4 * 4];
                    vp[0] = v.x; vp[1] = v.y; vp[2] = v.z; vp[3] = v.w;
                }
            }
            short4 b;
            b.x = f2bf(vp[0]); b.y = f2bf(vp[1]); b.z = f2bf(vp[2]); b.w = f2bf(vp[3]);
            if (WRITEX && grow < Nrows)
                *(short4*)&Xout[(size_t)grow * 128 + c4 * 4] = b;
            *(short4*)&Xs[r * KP + c4 * 4] = b;
        }
    }
    {
        constexpr int UNITS = (DOUT + 16) * 16;
        #pragma unroll
        for (int p = 0; p < UNITS / 256; p++) {
            int u = tid + p * 256;
            int n = u >> 4;
            int kc = (u & 15) * 8;
            bf16x8 v = *(const bf16x8*)&Wt[n * 128 + kc];
            *(bf16x8*)&Ws[n * KP + kc] = v;
        }
    }
    __syncthreads();

    const int lane = tid & 63;
    const int wv = tid >> 6;
    const int m0 = wv * 32;
    const int ln = lane & 15;
    const int quad = lane >> 4;

    floatx4 acc[2][CTT];
    #pragma unroll
    for (int mt = 0; mt < 2; mt++)
        #pragma unroll
        for (int ct = 0; ct < CTT; ct++) acc[mt][ct] = (floatx4){0.f, 0.f, 0.f, 0.f};

    #pragma unroll
    for (int ks = 0; ks < 4; ks++) {
        int ko = ks * 32 + quad * 8;
        bf16x8 a0 = *(const bf16x8*)&Xs[(m0 + ln) * KP + ko];
        bf16x8 a1 = *(const bf16x8*)&Xs[(m0 + 16 + ln) * KP + ko];
        #pragma unroll
        for (int ct = 0; ct < CTT; ct++) {
            bf16x8 b = *(const bf16x8*)&Ws[(ct * 16 + ln) * KP + ko];
            acc[0][ct] = __builtin_amdgcn_mfma_f32_16x16x32_bf16(a0, b, acc[0][ct], 0, 0, 0);
            acc[1][ct] = __builtin_amdgcn_mfma_f32_16x16x32_bf16(a1, b, acc[1][ct], 0, 0, 0);
        }
    }

    #pragma unroll
    for (int mt = 0; mt < 2; mt++) {
        #pragma unroll
        for (int r = 0; r < 4; r++) {
            int grow = row0 + m0 + mt * 16 + quad * 4 + r;
            if (grow < Nrows) {
                #pragma unroll
                for (int ct = 0; ct < CT; ct++)
                    Hout[(size_t)grow * DOUT + ct * 16 + ln] = f2bf(acc[mt][ct][r]);
                float aug = acc[mt][CT][r];
                if (DOUT == 128) {
                    if (ln < 8) als[grow * 8 + ln] = aug;
                    else        ald[grow * 8 + (ln - 8)] = aug;
                } else {
                    if (ln == 0) als[grow] = aug;
                    else if (ln == 1) ald[grow] = aug;
                }
            }
        }
    }
}

// ---------------- aggregate: half-wave per node, int4 row loads, 2 edge subgroups -----
// Lane f (0..31): subgroup g2=f>>4 handles edges k+g2, k+2+g2; slice q=f&15 covers
// feats 8q..8q+7. One int4 gather retires an edge for 16 lanes -> 1 VMEM/edge total.

__global__ __launch_bounds__(256) void k_agg(const int* __restrict__ rowptr,
                                             const int* __restrict__ col,
                                             const short* __restrict__ Hb,
                                             const float* __restrict__ als,
                                             const float* __restrict__ ald,
                                             const float* __restrict__ bias,
                                             short* __restrict__ out,
                                             float* __restrict__ part, int N) {
    __shared__ float red[8][128];
    const int wv = threadIdx.x >> 6;
    const int lane = threadIdx.x & 63;
    const int g = lane >> 5;          // node slot within wave
    const int f = lane & 31;
    const int g2 = f >> 4;            // edge subgroup
    const int q = f & 15;             // int4 slice -> feats 8q..8q+7
    const int h = q >> 1;             // head
    const int node = blockIdx.x * 8 + wv * 2 + g;
    const int4* H4 = (const int4*)Hb;

    int j = 0, deg = 0;
    float aldv = 0.f;
    if (node < N) {
        j = rowptr[node];
        deg = rowptr[node + 1] - j;
        aldv = ald[node * 8 + h];
    }
    float s = 0.f;
    float a[8] = {0.f, 0.f, 0.f, 0.f, 0.f, 0.f, 0.f, 0.f};

    int done = 0;
    while (__any(done < deg)) {
        int take = deg - done;
        if (take > 32) take = 32;
        if (take < 0) take = 0;
        int li = (f < take) ? f : (take - 1);
        if (li < 0) li = 0;
        int cbuf = col[j + done + li];        // lane f holds col[j+done+f] (clamped)
        for (int k = 0; __any(k < take); k += 4) {
            int e0 = k + g2, e1 = k + 2 + g2;
            int c0 = __shfl(cbuf, e0, 32);
            int c1 = __shfl(cbuf, e1, 32);
            float aw0 = als[c0 * 8 + h];
            float aw1 = als[c1 * 8 + h];
            int4 p0 = H4[c0 * 16 + q];
            int4 p1 = H4[c1 * 16 + q];
            float x0 = aw0 + aldv; x0 = LRELU(x0);
            float x1 = aw1 + aldv; x1 = LRELU(x1);
            float w0 = (e0 < take) ? __expf(x0) : 0.f;
            float w1 = (e1 < take) ? __expf(x1) : 0.f;
            s += w0;
            a[0] += w0 * bflo(p0.x); a[1] += w0 * bfhi(p0.x);
            a[2] += w0 * bflo(p0.y); a[3] += w0 * bfhi(p0.y);
            a[4] += w0 * bflo(p0.z); a[5] += w0 * bfhi(p0.z);
            a[6] += w0 * bflo(p0.w); a[7] += w0 * bfhi(p0.w);
            s += w1;
            a[0] += w1 * bflo(p1.x); a[1] += w1 * bfhi(p1.x);
            a[2] += w1 * bflo(p1.y); a[3] += w1 * bfhi(p1.y);
            a[4] += w1 * bflo(p1.z); a[5] += w1 * bfhi(p1.z);
            a[6] += w1 * bflo(p1.w); a[7] += w1 * bfhi(p1.w);
        }
        done += take;
    }

    // combine the two edge subgroups (lanes f and f^16 share slice q)
    s += __shfl_xor(s, 16, 32);
    #pragma unroll
    for (int i = 0; i < 8; i++) a[i] += __shfl_xor(a[i], 16, 32);

    float o[8];
    #pragma unroll
    for (int i = 0; i < 8; i++) o[i] = 0.f;
    if (node < N) {
        float4 bv0 = ((const float4*)bias)[2 * q];
        float4 bv1 = ((const float4*)bias)[2 * q + 1];
        float inv = 1.f / (s + 1e-16f);
        o[0] = a[0] * inv + bv0.x;
        o[1] = a[1] * inv + bv0.y;
        o[2] = a[2] * inv + bv0.z;
        o[3] = a[3] * inv + bv0.w;
        o[4] = a[4] * inv + bv1.x;
        o[5] = a[5] * inv + bv1.y;
        o[6] = a[6] * inv + bv1.z;
        o[7] = a[7] * inv + bv1.w;
        if (g2 == 0) {
            int4 pk;
            pk.x = (int)((unsigned short)f2bf(o[0]) | ((unsigned)(unsigned short)f2bf(o[1]) << 16));
            pk.y = (int)((unsigned short)f2bf(o[2]) | ((unsigned)(unsigned short)f2bf(o[3]) << 16));
            pk.z = (int)((unsigned short)f2bf(o[4]) | ((unsigned)(unsigned short)f2bf(o[5]) << 16));
            pk.w = (int)((unsigned short)f2bf(o[6]) | ((unsigned)(unsigned short)f2bf(o[7]) << 16));
            ((int4*)out)[(size_t)node * 16 + q] = pk;
        }
    }
    const int rrow = wv * 2 + g;
    // both subgroups hold identical o[]; split the 8 stores between them
    #pragma unroll
    for (int i = 0; i < 4; i++)
        red[rrow][8 * q + 4 * g2 + i] = o[4 * g2 + i];
    __syncthreads();
    if (threadIdx.x < 128) {
        int c = threadIdx.x;
        float s2 = 0.f, qq = 0.f;
        #pragma unroll
        for (int r = 0; r < 8; r++) {
            float v = red[r][c];
            s2 += v;
            qq += v * v;
        }
        float* slot = part + (blockIdx.x & 63) * 256;
        atomicAdd(&slot[c], s2);
        atomicAdd(&slot[128 + c], qq);
    }
}

// ---------------- reduce partials -> (scale, shift); re-zero part ----------------

__global__ __launch_bounds__(128) void k_bnreduce(float* __restrict__ part,
                                                  const float* __restrict__ g,
                                                  const float* __restrict__ bt,
                                                  float invN, float2* __restrict__ ss) {
    int c = threadIdx.x;
    float s = 0.f, q = 0.f;
    #pragma unroll
    for (int k = 0; k < 64; k++) {
        s += part[k * 256 + c];
        q += part[k * 256 + 128 + c];
    }
    #pragma unroll
    for (int k = 0; k < 64; k++) {
        part[k * 256 + c] = 0.f;
        part[k * 256 + 128 + c] = 0.f;
    }
    float mu = s * invN;
    float var = q * invN - mu * mu;
    float scale = rsqrtf(var + 1e-5f) * g[c];
    ss[c] = make_float2(scale, bt[c] - mu * scale);
}

// ---------------- layer-2: half-wave per node, int4 loads, 4 edge subgroups + LN ------
// Lane f: subgroup g4=f>>3 handles edges k+g4, k+4+g4; slice q=f&7 covers feats
// 8q..8q+7 of the 64-feat row. Combine via shfl_xor(8) + shfl_xor(16).

__global__ __launch_bounds__(256) void k_agg2ln(const int* __restrict__ rowptr,
                                                const int* __restrict__ col,
                                                const short* __restrict__ Hb2,
                                                const float* __restrict__ als,
                                                const float* __restrict__ ald,
                                                const float* __restrict__ b2,
                                                const float* __restrict__ lng,
                                                const float* __restrict__ lnb,
                                                float* __restrict__ out, int N) {
    const int wv = threadIdx.x >> 6;
    const int lane = threadIdx.x & 63;
    const int g = lane >> 5;
    const int f = lane & 31;
    const int g4 = f >> 3;            // edge subgroup (0..3)
    const int q = f & 7;              // int4 slice -> feats 8q..8q+7
    const int node = blockIdx.x * 8 + wv * 2 + g;
    const int4* H4 = (const int4*)Hb2;
    const bool vn = node < N;

    int j = 0, deg = 0;
    float aldv = 0.f;
    if (vn) {
        j = rowptr[node];
        deg = rowptr[node + 1] - j;
        aldv = ald[node];
    }
    float s = 0.f;
    float a[8] = {0.f, 0.f, 0.f, 0.f, 0.f, 0.f, 0.f, 0.f};

    int done = 0;
    while (__any(done < deg)) {
        int take = deg - done;
        if (take > 32) take = 32;
        if (take < 0) take = 0;
        int li = (f < take) ? f : (take - 1);
        if (li < 0) li = 0;
        int cbuf = col[j + done + li];
        for (int k = 0; __any(k < take); k += 8) {
            int e0 = k + g4, e1 = k + 4 + g4;
            int c0 = __shfl(cbuf, e0, 32);
            int c1 = __shfl(cbuf, e1, 32);
            float aw0 = als[c0];
            float aw1 = als[c1];
            int4 p0 = H4[c0 * 8 + q];
            int4 p1 = H4[c1 * 8 + q];
            float x0 = aw0 + aldv; x0 = LRELU(x0);
            float x1 = aw1 + aldv; x1 = LRELU(x1);
            float w0 = (e0 < take) ? __expf(x0) : 0.f;
            float w1 = (e1 < take) ? __expf(x1) : 0.f;
            s += w0;
            a[0] += w0 * bflo(p0.x); a[1] += w0 * bfhi(p0.x);
            a[2] += w0 * bflo(p0.y); a[3] += w0 * bfhi(p0.y);
            a[4] += w0 * bflo(p0.z); a[5] += w0 * bfhi(p0.z);
            a[6] += w0 * bflo(p0.w); a[7] += w0 * bfhi(p0.w);
            s += w1;
            a[0] += w1 * bflo(p1.x); a[1] += w1 * bfhi(p1.x);
            a[2] += w1 * bflo(p1.y); a[3] += w1 * bfhi(p1.y);
            a[4] += w1 * bflo(p1.z); a[5] += w1 * bfhi(p1.z);
            a[6] += w1 * bflo(p1.w); a[7] += w1 * bfhi(p1.w);
        }
        done += take;
    }

    // combine the four edge subgroups (same q across g4)
    s += __shfl_xor(s, 8, 32);
    s += __shfl_xor(s, 16, 32);
    #pragma unroll
    for (int i = 0; i < 8; i++) {
        a[i] += __shfl_xor(a[i], 8, 32);
        a[i] += __shfl_xor(a[i], 16, 32);
    }

    if (!vn) return;
    float inv = 1.f / (s + 1e-16f);
    float4 bv0 = ((const float4*)b2)[2 * q];
    float4 bv1 = ((const float4*)b2)[2 * q + 1];
    float v[8];
    v[0] = a[0] * inv + bv0.x;
    v[1] = a[1] * inv + bv0.y;
    v[2] = a[2] * inv + bv0.z;
    v[3] = a[3] * inv + bv0.w;
    v[4] = a[4] * inv + bv1.x;
    v[5] = a[5] * inv + bv1.y;
    v[6] = a[6] * inv + bv1.z;
    v[7] = a[7] * inv + bv1.w;
    float su = 0.f, sq = 0.f;
    #pragma unroll
    for (int i = 0; i < 8; i++) { su += v[i]; sq += v[i] * v[i]; }
    // reduce across q (bits 0..2 of f)
    su += __shfl_xor(su, 1, 32); sq += __shfl_xor(sq, 1, 32);
    su += __shfl_xor(su, 2, 32); sq += __shfl_xor(sq, 2, 32);
    su += __shfl_xor(su, 4, 32); sq += __shfl_xor(sq, 4, 32);
    float mu = su * (1.f / 64.f);
    float var = sq * (1.f / 64.f) - mu * mu;
    float r = rsqrtf(var + 1e-5f);
    if (g4 == 0) {
        float4 lg0 = ((const float4*)lng)[2 * q];
        float4 lg1 = ((const float4*)lng)[2 * q + 1];
        float4 lb0 = ((const float4*)lnb)[2 * q];
        float4 lb1 = ((const float4*)lnb)[2 * q + 1];
        float4 o0, o1;
        o0.x = (v[0] - mu) * r * lg0.x + lb0.x;
        o0.y = (v[1] - mu) * r * lg0.y + lb0.y;
        o0.z = (v[2] - mu) * r * lg0.z + lb0.z;
        o0.w = (v[3] - mu) * r * lg0.w + lb0.w;
        o1.x = (v[4] - mu) * r * lg1.x + lb1.x;
        o1.y = (v[5] - mu) * r * lg1.y + lb1.y;
        o1.z = (v[6] - mu) * r * lg1.z + lb1.z;
        o1.w = (v[7] - mu) * r * lg1.w + lb1.w;
        ((float4*)out)[(size_t)node * 16 + 2 * q] = o0;
        ((float4*)out)[(size_t)node * 16 + 2 * q + 1] = o1;
    }
}

// ---------------- launch ----------------

extern "C" void kernel_launch(void* const* d_in, const int* in_sizes, int n_in,
                              void* d_out, int out_size, void* d_ws, size_t ws_size,
                              hipStream_t stream) {
    const float* x   = (const float*)d_in[0];
    const int*   ei  = (const int*)d_in[1];
    const float* W0  = (const float*)d_in[2];
    const float* as0 = (const float*)d_in[3];
    const float* ad0 = (const float*)d_in[4];
    const float* b0  = (const float*)d_in[5];
    const float* g0  = (const float*)d_in[6];
    const float* bt0 = (const float*)d_in[7];
    const float* W1  = (const float*)d_in[8];
    const float* as1 = (const float*)d_in[9];
    const float* ad1 = (const float*)d_in[10];
    const float* b1  = (const float*)d_in[11];
    const float* g1  = (const float*)d_in[12];
    const float* bt1 = (const float*)d_in[13];
    const float* W2  = (const float*)d_in[14];
    const float* as2 = (const float*)d_in[15];
    const float* ad2 = (const float*)d_in[16];
    const float* b2  = (const float*)d_in[17];
    const float* lng = (const float*)d_in[18];
    const float* lnb = (const float*)d_in[19];

    const int N = in_sizes[0] / 128;
    const int E = in_sizes[1] / 2;
    const int Etot = E + N;
    const int nb = (N + 127) >> 7;     // buckets of 128 nodes (requires nb <= 1024)

    char* p = (char*)d_ws;
    auto carve = [&](size_t bytes) {
        void* q = (void*)p;
        p += (bytes + 255) & ~(size_t)255;
        return q;
    };
    short* Hb     = (short*)carve((size_t)N * 128 * 2);
    short* aggb   = (short*)carve((size_t)N * 128 * 2);
    short* x1b    = (short*)carve((size_t)N * 128 * 2);
    float* als    = (float*)carve((size_t)N * 8 * 4);
    float* ald    = (float*)carve((size_t)N * 8 * 4);
    int*   rowptr = (int*)carve((size_t)(N + 1) * 4);
    int*   bucket_cnt = (int*)carve(1024 * 4);
    float* part   = (float*)carve(64 * 256 * 4);
    int*   col    = (int*)carve((size_t)(Etot + 64) * 4);
    int2*  ebin   = (int2*)carve((size_t)E * 8);
    int*   ebase  = (int*)carve(1028 * 4);
    int*   bcursor= (int*)carve(1024 * 4);
    float2* ss    = (float2*)carve(128 * 8);
    short* Wt0    = (short*)carve(144 * 128 * 2);
    short* Wt1    = (short*)carve(144 * 128 * 2);
    short* Wt2    = (short*)carve(80 * 128 * 2);

    const float invN = 1.f / (float)N;
    const int bb = (E + 256 * EPT - 1) / (256 * EPT);
    const int wpb = (128 * 128 + 64 * 128 + 128 * 8 + 128 + 255) / 256;

    k_wprep<<<wpb, 256, 0, stream>>>(W0, W1, W2, as0, ad0, as1, ad1, as2, ad2,
                                     Wt0, Wt1, Wt2, part, bucket_cnt);
    k_binc<<<bb, 256, 0, stream>>>(ei + E, E, nb, bucket_cnt);
    k_scanb<<<1, 256, 0, stream>>>(bucket_cnt, nb, E, Etot, N, ebase, bcursor, rowptr);
    k_bin<<<bb, 256, 0, stream>>>(ei, ei + E, E, nb, bcursor, ebin);
    k_cfill2<<<nb, 256, 0, stream>>>(ebase, ebin, rowptr, col, N);

    const int gb = (N + 127) / 128;
    const int ab = (N + 7) / 8;

    // ---- layer 0 ----
    k_gemm<128, false, false, false><<<gb, 256, 0, stream>>>(x, Wt0, Hb, nullptr, nullptr,
                                                             nullptr, als, ald, N);
    k_agg<<<ab, 256, 0, stream>>>(rowptr, col, Hb, als, ald, b0, aggb, part, N);
    k_bnreduce<<<1, 128, 0, stream>>>(part, g0, bt0, invN, ss);

    // ---- layer 1 (BN-apply fused into GEMM staging; agg/x1 bf16) ----
    k_gemm<128, true, false, true><<<gb, 256, 0, stream>>>(aggb, Wt1, Hb, ss, x, x1b,
                                                           als, ald, N);
    k_agg<<<ab, 256, 0, stream>>>(rowptr, col, Hb, als, ald, b1, aggb, part, N);
    k_bnreduce<<<1, 128, 0, stream>>>(part, g1, bt1, invN, ss);

    // ---- layer 2 (BN-apply fused; bf16 residual; x2 never materialized) ----
    k_gemm<64, true, true, false><<<gb, 256, 0, stream>>>(aggb, Wt2, Hb, ss, x1b, nullptr,
                                                          als, ald, N);
    k_agg2ln<<<ab, 256, 0, stream>>>(rowptr, col, Hb, als, ald, b2, lng, lnb,
                                     (float*)d_out, N);
}

// Round 11
// 355.658 us; speedup vs baseline: 7.8743x; 1.0233x over previous
//
#include <hip/hip_runtime.h>
#include <hip/hip_bf16.h>

#define LRELU(e) ((e) > 0.f ? (e) : 0.2f * (e))

typedef __attribute__((ext_vector_type(8))) short bf16x8;
typedef __attribute__((ext_vector_type(4))) float floatx4;

constexpr int ESTRIDE = 2048;   // edge slots per bucket region in ebin
constexpr int CSTRIDE = 2176;   // col slots per bucket (128 self loops + ESTRIDE)

__device__ inline short f2bf(float f) {
    union { float f; unsigned u; } v; v.f = f;
    unsigned r = v.u + 0x7fffu + ((v.u >> 16) & 1u);
    return (short)(r >> 16);
}
__device__ inline float bflo(int p) {
    union { unsigned u; float f; } v; v.u = (unsigned)p << 16; return v.f;
}
__device__ inline float bfhi(int p) {
    union { unsigned u; float f; } v; v.u = (unsigned)p & 0xffff0000u; return v.f;
}
__device__ inline float bf2f(unsigned short s) {
    union { unsigned u; float f; } v; v.u = (unsigned)s << 16; return v.f;
}

// ---------------- weight prep + workspace zeroing + bcursor init ----------------

__global__ __launch_bounds__(256) void k_wprep(const float* __restrict__ W0,
                                               const float* __restrict__ W1,
                                               const float* __restrict__ W2,
                                               const float* __restrict__ as0,
                                               const float* __restrict__ ad0,
                                               const float* __restrict__ as1,
                                               const float* __restrict__ ad1,
                                               const float* __restrict__ as2,
                                               const float* __restrict__ ad2,
                                               short* __restrict__ Wt0,
                                               short* __restrict__ Wt1,
                                               short* __restrict__ Wt2,
                                               float* __restrict__ part0,
                                               float* __restrict__ part1,
                                               int* __restrict__ bcursor) {
    int i = blockIdx.x * blockDim.x + threadIdx.x;
    if (i < 16384) part0[i] = 0.f;
    else if (i < 32768) part1[i - 16384] = 0.f;
    if (i < 1024) bcursor[i] = i * ESTRIDE;

    if (i < 128 * 128) {
        int n = i >> 7, k = i & 127;
        Wt0[n * 128 + k] = f2bf(W0[k * 128 + n]);
        Wt1[n * 128 + k] = f2bf(W1[k * 128 + n]);
    } else if (i < 128 * 128 + 64 * 128) {
        int j = i - 128 * 128;
        int n = j >> 7, k = j & 127;
        Wt2[n * 128 + k] = f2bf(W2[k * 64 + n]);
    } else if (i < 128 * 128 + 64 * 128 + 128 * 8) {
        int j = i - (128 * 128 + 64 * 128);
        int k = j >> 3, h = j & 7;
        float s0 = 0.f, d0 = 0.f, s1 = 0.f, d1 = 0.f;
        #pragma unroll
        for (int d = 0; d < 16; d++) {
            float w0 = W0[k * 128 + h * 16 + d];
            float w1 = W1[k * 128 + h * 16 + d];
            s0 += w0 * as0[h * 16 + d];
            d0 += w0 * ad0[h * 16 + d];
            s1 += w1 * as1[h * 16 + d];
            d1 += w1 * ad1[h * 16 + d];
        }
        Wt0[(128 + h) * 128 + k] = f2bf(s0);
        Wt0[(136 + h) * 128 + k] = f2bf(d0);
        Wt1[(128 + h) * 128 + k] = f2bf(s1);
        Wt1[(136 + h) * 128 + k] = f2bf(d1);
    } else if (i < 128 * 128 + 64 * 128 + 128 * 8 + 128) {
        int k = i - (128 * 128 + 64 * 128 + 128 * 8);
        float s = 0.f, d = 0.f;
        #pragma unroll
        for (int dd = 0; dd < 64; dd++) {
            float w = W2[k * 64 + dd];
            s += w * as2[dd];
            d += w * ad2[dd];
        }
        Wt2[64 * 128 + k] = f2bf(s);
        Wt2[65 * 128 + k] = f2bf(d);
        #pragma unroll
        for (int r = 66; r < 80; r++) Wt2[r * 128 + k] = 0;
    }
}

// ---------------- binned edge scatter into fixed-stride bucket regions ----------------
// Buckets of 128 dst nodes; nb <= 1024 (N <= 131072). bcursor pre-set to b*ESTRIDE.

constexpr int EPT = 16;

__global__ __launch_bounds__(256) void k_bin(const int* __restrict__ srcE,
                                             const int* __restrict__ dstE, int E, int nb,
                                             int* __restrict__ bcursor,
                                             int2* __restrict__ ebin) {
    __shared__ int cnt[1024];
    __shared__ int base[1024];
    for (int b = threadIdx.x; b < nb; b += 256) cnt[b] = 0;
    __syncthreads();
    int i0 = blockIdx.x * (256 * EPT) + threadIdx.x;
    int rb[EPT];
    #pragma unroll
    for (int k = 0; k < EPT; k++) {
        int i = i0 + k * 256;
        if (i < E) {
            int b = dstE[i] >> 7;
            rb[k] = (atomicAdd(&cnt[b], 1) << 10) | b;   // rank | bucket(10b)
        } else {
            rb[k] = -1;
        }
    }
    __syncthreads();
    for (int b = threadIdx.x; b < nb; b += 256) {
        int c = cnt[b];
        base[b] = c ? atomicAdd(&bcursor[b], c) : 0;
    }
    __syncthreads();
    #pragma unroll
    for (int k = 0; k < EPT; k++) {
        int i = i0 + k * 256;
        if (i < E) {
            int v = rb[k];
            int b = v & 1023;
            int r = v >> 10;
            int idx = base[b] + r;
            if (idx < (b + 1) * ESTRIDE)                 // defensive clamp
                ebin[idx] = make_int2(srcE[i], dstE[i]);
        }
    }
}

// ---------------- CSR fill: per bucket; local degree count + scan -> rowptr/rowend ----

__global__ __launch_bounds__(256) void k_cfill2(const int* __restrict__ bcursor,
                                                const int2* __restrict__ ebin,
                                                int* __restrict__ rowptr,
                                                int* __restrict__ rowend,
                                                int* __restrict__ col, int N) {
    const int b = blockIdx.x;
    const int n0 = b << 7;
    int nn = N - n0; if (nn > 128) nn = 128;
    __shared__ int cnt[128];
    __shared__ int wtot[2];
    const int t = threadIdx.x;
    if (t < 128) cnt[t] = 0;
    __syncthreads();
    const int e0 = b * ESTRIDE;
    int e1 = bcursor[b];
    if (e1 > e0 + ESTRIDE) e1 = e0 + ESTRIDE;
    for (int i = e0 + t; i < e1; i += 256) {
        atomicAdd(&cnt[ebin[i].y & 127], 1);
    }
    __syncthreads();
    int v = (t < 128) ? cnt[t] : 0;
    int lane = t & 63;
    int x = v;
    #pragma unroll
    for (int off = 1; off < 64; off <<= 1) {
        int y = __shfl_up(x, off, 64);
        if (lane >= off) x += y;
    }
    if (t < 128 && lane == 63) wtot[t >> 6] = x;
    __syncthreads();
    int excl = x - v + ((t >= 64 && t < 128) ? wtot[0] : 0);
    if (t < nn) {
        int rp = b * CSTRIDE + t + excl;
        rowptr[n0 + t] = rp;
        rowend[n0 + t] = rp + 1 + v;
        col[rp] = n0 + t;            // self loop in first slot of its row
        cnt[t] = rp + 1;             // reuse cnt[] as per-node cursor
    }
    __syncthreads();
    for (int i = e0 + t; i < e1; i += 256) {
        int2 e = ebin[i];
        int p = atomicAdd(&cnt[e.y & 127], 1);
        col[p] = e.x;
    }
}

// ---------------- MFMA bf16 GEMM + fused BN stats-reduce + BN-apply -------------------
// HASBN: computes (scale,shift) from part (written by previous k_agg) in-block, then
// y = relu(X*scale+shift)+Xres. RESBF16: Xres bf16. WRITEX: store y to Xout.

template <int DOUT, bool HASBN, bool RESBF16, bool WRITEX>
__global__ __launch_bounds__(256) void k_gemm(const void* __restrict__ Xv,
                                              const short* __restrict__ Wt,
                                              short* __restrict__ Hout,
                                              const void* __restrict__ Xresv,
                                              short* __restrict__ Xout,
                                              float* __restrict__ als,
                                              float* __restrict__ ald, int Nrows,
                                              const float* __restrict__ part,
                                              const float* __restrict__ bng,
                                              const float* __restrict__ bnbt,
                                              float invN) {
    constexpr int KP = 136;
    constexpr int CT = DOUT / 16;
    constexpr int CTT = CT + 1;
    __shared__ __align__(16) short Xs[128 * KP];
    __shared__ __align__(16) short Ws[(DOUT + 16) * KP];
    __shared__ float2 ssl[128];
    __shared__ float tmp[256];

    const int tid = threadIdx.x;
    const int row0 = blockIdx.x * 128;

    if (HASBN) {
        int c = tid & 127, half = tid >> 7;
        float acc = 0.f;
        #pragma unroll
        for (int k = 0; k < 64; k++) acc += part[k * 256 + half * 128 + c];
        tmp[tid] = acc;
        __syncthreads();
        if (tid < 128) {
            float mu = tmp[tid] * invN;
            float var = tmp[128 + tid] * invN - mu * mu;
            float scale = rsqrtf(var + 1e-5f) * bng[tid];
            ssl[tid] = make_float2(scale, bnbt[tid] - mu * scale);
        }
        __syncthreads();
    }

    {
        int c4 = tid & 31;
        int r0 = tid >> 5;
        float2 ssv[4];
        if (HASBN) {
            #pragma unroll
            for (int j = 0; j < 4; j++) ssv[j] = ssl[c4 * 4 + j];
        }
        #pragma unroll
        for (int p = 0; p < 16; p++) {
            int r = r0 + p * 8;
            int grow = row0 + r;
            float vp[4] = {0.f, 0.f, 0.f, 0.f};
            if (grow < Nrows) {
                if (HASBN) {
                    short4 xb = *(const short4*)&((const short*)Xv)[(size_t)grow * 128 + c4 * 4];
                    vp[0] = bf2f((unsigned short)xb.x);
                    vp[1] = bf2f((unsigned short)xb.y);
                    vp[2] = bf2f((unsigned short)xb.z);
                    vp[3] = bf2f((unsigned short)xb.w);
                    float xr[4];
                    if (RESBF16) {
                        short4 rb = *(const short4*)&((const short*)Xresv)[(size_t)grow * 128 + c4 * 4];
                        xr[0] = bf2f((unsigned short)rb.x);
                        xr[1] = bf2f((unsigned short)rb.y);
                        xr[2] = bf2f((unsigned short)rb.z);
                        xr[3] = bf2f((unsigned short)rb.w);
                    } else {
                        float4 rf = *(const float4*)&((const float*)Xresv)[(size_t)grow * 128 + c4 * 4];
                        xr[0] = rf.x; xr[1] = rf.y; xr[2] = rf.z; xr[3] = rf.w;
                    }
                    #pragma unroll
                    for (int j = 0; j < 4; j++)
                        vp[j] = fmaxf(vp[j] * ssv[j].x + ssv[j].y, 0.f) + xr[j];
                } else {
                    float4 v = *(const float4*)&((const float*)Xv)[(size_t)grow * 128 + c4 * 4];
                    vp[0] = v.x; vp[1] = v.y; vp[2] = v.z; vp[3] = v.w;
                }
            }
            short4 b;
            b.x = f2bf(vp[0]); b.y = f2bf(vp[1]); b.z = f2bf(vp[2]); b.w = f2bf(vp[3]);
            if (WRITEX && grow < Nrows)
                *(short4*)&Xout[(size_t)grow * 128 + c4 * 4] = b;
            *(short4*)&Xs[r * KP + c4 * 4] = b;
        }
    }
    {
        constexpr int UNITS = (DOUT + 16) * 16;
        #pragma unroll
        for (int p = 0; p < UNITS / 256; p++) {
            int u = tid + p * 256;
            int n = u >> 4;
            int kc = (u & 15) * 8;
            bf16x8 v = *(const bf16x8*)&Wt[n * 128 + kc];
            *(bf16x8*)&Ws[n * KP + kc] = v;
        }
    }
    __syncthreads();

    const int lane = tid & 63;
    const int wv = tid >> 6;
    const int m0 = wv * 32;
    const int ln = lane & 15;
    const int quad = lane >> 4;

    floatx4 acc[2][CTT];
    #pragma unroll
    for (int mt = 0; mt < 2; mt++)
        #pragma unroll
        for (int ct = 0; ct < CTT; ct++) acc[mt][ct] = (floatx4){0.f, 0.f, 0.f, 0.f};

    #pragma unroll
    for (int ks = 0; ks < 4; ks++) {
        int ko = ks * 32 + quad * 8;
        bf16x8 a0 = *(const bf16x8*)&Xs[(m0 + ln) * KP + ko];
        bf16x8 a1 = *(const bf16x8*)&Xs[(m0 + 16 + ln) * KP + ko];
        #pragma unroll
        for (int ct = 0; ct < CTT; ct++) {
            bf16x8 b = *(const bf16x8*)&Ws[(ct * 16 + ln) * KP + ko];
            acc[0][ct] = __builtin_amdgcn_mfma_f32_16x16x32_bf16(a0, b, acc[0][ct], 0, 0, 0);
            acc[1][ct] = __builtin_amdgcn_mfma_f32_16x16x32_bf16(a1, b, acc[1][ct], 0, 0, 0);
        }
    }

    #pragma unroll
    for (int mt = 0; mt < 2; mt++) {
        #pragma unroll
        for (int r = 0; r < 4; r++) {
            int grow = row0 + m0 + mt * 16 + quad * 4 + r;
            if (grow < Nrows) {
                #pragma unroll
                for (int ct = 0; ct < CT; ct++)
                    Hout[(size_t)grow * DOUT + ct * 16 + ln] = f2bf(acc[mt][ct][r]);
                float aug = acc[mt][CT][r];
                if (DOUT == 128) {
                    if (ln < 8) als[grow * 8 + ln] = aug;
                    else        ald[grow * 8 + (ln - 8)] = aug;
                } else {
                    if (ln == 0) als[grow] = aug;
                    else if (ln == 1) ald[grow] = aug;
                }
            }
        }
    }
}

// ---------------- aggregate: half-wave per node, int4 row loads, 2 edge subgroups -----

__global__ __launch_bounds__(256) void k_agg(const int* __restrict__ rowptr,
                                             const int* __restrict__ rowend,
                                             const int* __restrict__ col,
                                             const short* __restrict__ Hb,
                                             const float* __restrict__ als,
                                             const float* __restrict__ ald,
                                             const float* __restrict__ bias,
                                             short* __restrict__ out,
                                             float* __restrict__ part, int N) {
    __shared__ float red[8][128];
    const int wv = threadIdx.x >> 6;
    const int lane = threadIdx.x & 63;
    const int g = lane >> 5;          // node slot within wave
    const int f = lane & 31;
    const int g2 = f >> 4;            // edge subgroup
    const int q = f & 15;             // int4 slice -> feats 8q..8q+7
    const int h = q >> 1;             // head
    const int node = blockIdx.x * 8 + wv * 2 + g;
    const int4* H4 = (const int4*)Hb;

    int j = 0, deg = 0;
    float aldv = 0.f;
    if (node < N) {
        j = rowptr[node];
        deg = rowend[node] - j;
        aldv = ald[node * 8 + h];
    }
    float s = 0.f;
    float a[8] = {0.f, 0.f, 0.f, 0.f, 0.f, 0.f, 0.f, 0.f};

    int done = 0;
    while (__any(done < deg)) {
        int take = deg - done;
        if (take > 32) take = 32;
        if (take < 0) take = 0;
        int li = (f < take) ? f : (take - 1);
        if (li < 0) li = 0;
        int cbuf = col[j + done + li];        // lane f holds col[j+done+f] (clamped)
        for (int k = 0; __any(k < take); k += 4) {
            int e0 = k + g2, e1 = k + 2 + g2;
            int c0 = __shfl(cbuf, e0, 32);
            int c1 = __shfl(cbuf, e1, 32);
            float aw0 = als[c0 * 8 + h];
            float aw1 = als[c1 * 8 + h];
            int4 p0 = H4[c0 * 16 + q];
            int4 p1 = H4[c1 * 16 + q];
            float x0 = aw0 + aldv; x0 = LRELU(x0);
            float x1 = aw1 + aldv; x1 = LRELU(x1);
            float w0 = (e0 < take) ? __expf(x0) : 0.f;
            float w1 = (e1 < take) ? __expf(x1) : 0.f;
            s += w0;
            a[0] += w0 * bflo(p0.x); a[1] += w0 * bfhi(p0.x);
            a[2] += w0 * bflo(p0.y); a[3] += w0 * bfhi(p0.y);
            a[4] += w0 * bflo(p0.z); a[5] += w0 * bfhi(p0.z);
            a[6] += w0 * bflo(p0.w); a[7] += w0 * bfhi(p0.w);
            s += w1;
            a[0] += w1 * bflo(p1.x); a[1] += w1 * bfhi(p1.x);
            a[2] += w1 * bflo(p1.y); a[3] += w1 * bfhi(p1.y);
            a[4] += w1 * bflo(p1.z); a[5] += w1 * bfhi(p1.z);
            a[6] += w1 * bflo(p1.w); a[7] += w1 * bfhi(p1.w);
        }
        done += take;
    }

    // combine the two edge subgroups (lanes f and f^16 share slice q)
    s += __shfl_xor(s, 16, 32);
    #pragma unroll
    for (int i = 0; i < 8; i++) a[i] += __shfl_xor(a[i], 16, 32);

    float o[8];
    #pragma unroll
    for (int i = 0; i < 8; i++) o[i] = 0.f;
    if (node < N) {
        float4 bv0 = ((const float4*)bias)[2 * q];
        float4 bv1 = ((const float4*)bias)[2 * q + 1];
        float inv = 1.f / (s + 1e-16f);
        o[0] = a[0] * inv + bv0.x;
        o[1] = a[1] * inv + bv0.y;
        o[2] = a[2] * inv + bv0.z;
        o[3] = a[3] * inv + bv0.w;
        o[4] = a[4] * inv + bv1.x;
        o[5] = a[5] * inv + bv1.y;
        o[6] = a[6] * inv + bv1.z;
        o[7] = a[7] * inv + bv1.w;
        if (g2 == 0) {
            int4 pk;
            pk.x = (int)((unsigned short)f2bf(o[0]) | ((unsigned)(unsigned short)f2bf(o[1]) << 16));
            pk.y = (int)((unsigned short)f2bf(o[2]) | ((unsigned)(unsigned short)f2bf(o[3]) << 16));
            pk.z = (int)((unsigned short)f2bf(o[4]) | ((unsigned)(unsigned short)f2bf(o[5]) << 16));
            pk.w = (int)((unsigned short)f2bf(o[6]) | ((unsigned)(unsigned short)f2bf(o[7]) << 16));
            ((int4*)out)[(size_t)node * 16 + q] = pk;
        }
    }
    const int rrow = wv * 2 + g;
    // both subgroups hold identical o[]; split the 8 stores between them
    #pragma unroll
    for (int i = 0; i < 4; i++)
        red[rrow][8 * q + 4 * g2 + i] = o[4 * g2 + i];
    __syncthreads();
    if (threadIdx.x < 128) {
        int c = threadIdx.x;
        float s2 = 0.f, qq = 0.f;
        #pragma unroll
        for (int r = 0; r < 8; r++) {
            float v = red[r][c];
            s2 += v;
            qq += v * v;
        }
        float* slot = part + (blockIdx.x & 63) * 256;
        atomicAdd(&slot[c], s2);
        atomicAdd(&slot[128 + c], qq);
    }
}

// ---------------- layer-2: half-wave per node, int4 loads, 4 edge subgroups + LN ------

__global__ __launch_bounds__(256) void k_agg2ln(const int* __restrict__ rowptr,
                                                const int* __restrict__ rowend,
                                                const int* __restrict__ col,
                                                const short* __restrict__ Hb2,
                                                const float* __restrict__ als,
                                                const float* __restrict__ ald,
                                                const float* __restrict__ b2,
                                                const float* __restrict__ lng,
                                                const float* __restrict__ lnb,
                                                float* __restrict__ out, int N) {
    const int wv = threadIdx.x >> 6;
    const int lane = threadIdx.x & 63;
    const int g = lane >> 5;
    const int f = lane & 31;
    const int g4 = f >> 3;            // edge subgroup (0..3)
    const int q = f & 7;              // int4 slice -> feats 8q..8q+7
    const int node = blockIdx.x * 8 + wv * 2 + g;
    const int4* H4 = (const int4*)Hb2;
    const bool vn = node < N;

    int j = 0, deg = 0;
    float aldv = 0.f;
    if (vn) {
        j = rowptr[node];
        deg = rowend[node] - j;
        aldv = ald[node];
    }
    float s = 0.f;
    float a[8] = {0.f, 0.f, 0.f, 0.f, 0.f, 0.f, 0.f, 0.f};

    int done = 0;
    while (__any(done < deg)) {
        int take = deg - done;
        if (take > 32) take = 32;
        if (take < 0) take = 0;
        int li = (f < take) ? f : (take - 1);
        if (li < 0) li = 0;
        int cbuf = col[j + done + li];
        for (int k = 0; __any(k < take); k += 8) {
            int e0 = k + g4, e1 = k + 4 + g4;
            int c0 = __shfl(cbuf, e0, 32);
            int c1 = __shfl(cbuf, e1, 32);
            float aw0 = als[c0];
            float aw1 = als[c1];
            int4 p0 = H4[c0 * 8 + q];
            int4 p1 = H4[c1 * 8 + q];
            float x0 = aw0 + aldv; x0 = LRELU(x0);
            float x1 = aw1 + aldv; x1 = LRELU(x1);
            float w0 = (e0 < take) ? __expf(x0) : 0.f;
            float w1 = (e1 < take) ? __expf(x1) : 0.f;
            s += w0;
            a[0] += w0 * bflo(p0.x); a[1] += w0 * bfhi(p0.x);
            a[2] += w0 * bflo(p0.y); a[3] += w0 * bfhi(p0.y);
            a[4] += w0 * bflo(p0.z); a[5] += w0 * bfhi(p0.z);
            a[6] += w0 * bflo(p0.w); a[7] += w0 * bfhi(p0.w);
            s += w1;
            a[0] += w1 * bflo(p1.x); a[1] += w1 * bfhi(p1.x);
            a[2] += w1 * bflo(p1.y); a[3] += w1 * bfhi(p1.y);
            a[4] += w1 * bflo(p1.z); a[5] += w1 * bfhi(p1.z);
            a[6] += w1 * bflo(p1.w); a[7] += w1 * bfhi(p1.w);
        }
        done += take;
    }

    // combine the four edge subgroups (same q across g4)
    s += __shfl_xor(s, 8, 32);
    s += __shfl_xor(s, 16, 32);
    #pragma unroll
    for (int i = 0; i < 8; i++) {
        a[i] += __shfl_xor(a[i], 8, 32);
        a[i] += __shfl_xor(a[i], 16, 32);
    }

    if (!vn) return;
    float inv = 1.f / (s + 1e-16f);
    float4 bv0 = ((const float4*)b2)[2 * q];
    float4 bv1 = ((const float4*)b2)[2 * q + 1];
    float v[8];
    v[0] = a[0] * inv + bv0.x;
    v[1] = a[1] * inv + bv0.y;
    v[2] = a[2] * inv + bv0.z;
    v[3] = a[3] * inv + bv0.w;
    v[4] = a[4] * inv + bv1.x;
    v[5] = a[5] * inv + bv1.y;
    v[6] = a[6] * inv + bv1.z;
    v[7] = a[7] * inv + bv1.w;
    float su = 0.f, sq = 0.f;
    #pragma unroll
    for (int i = 0; i < 8; i++) { su += v[i]; sq += v[i] * v[i]; }
    // reduce across q (bits 0..2 of f)
    su += __shfl_xor(su, 1, 32); sq += __shfl_xor(sq, 1, 32);
    su += __shfl_xor(su, 2, 32); sq += __shfl_xor(sq, 2, 32);
    su += __shfl_xor(su, 4, 32); sq += __shfl_xor(sq, 4, 32);
    float mu = su * (1.f / 64.f);
    float var = sq * (1.f / 64.f) - mu * mu;
    float r = rsqrtf(var + 1e-5f);
    if (g4 == 0) {
        float4 lg0 = ((const float4*)lng)[2 * q];
        float4 lg1 = ((const float4*)lng)[2 * q + 1];
        float4 lb0 = ((const float4*)lnb)[2 * q];
        float4 lb1 = ((const float4*)lnb)[2 * q + 1];
        float4 o0, o1;
        o0.x = (v[0] - mu) * r * lg0.x + lb0.x;
        o0.y = (v[1] - mu) * r * lg0.y + lb0.y;
        o0.z = (v[2] - mu) * r * lg0.z + lb0.z;
        o0.w = (v[3] - mu) * r * lg0.w + lb0.w;
        o1.x = (v[4] - mu) * r * lg1.x + lb1.x;
        o1.y = (v[5] - mu) * r * lg1.y + lb1.y;
        o1.z = (v[6] - mu) * r * lg1.z + lb1.z;
        o1.w = (v[7] - mu) * r * lg1.w + lb1.w;
        ((float4*)out)[(size_t)node * 16 + 2 * q] = o0;
        ((float4*)out)[(size_t)node * 16 + 2 * q + 1] = o1;
    }
}

// ---------------- launch ----------------

extern "C" void kernel_launch(void* const* d_in, const int* in_sizes, int n_in,
                              void* d_out, int out_size, void* d_ws, size_t ws_size,
                              hipStream_t stream) {
    const float* x   = (const float*)d_in[0];
    const int*   ei  = (const int*)d_in[1];
    const float* W0  = (const float*)d_in[2];
    const float* as0 = (const float*)d_in[3];
    const float* ad0 = (const float*)d_in[4];
    const float* b0  = (const float*)d_in[5];
    const float* g0  = (const float*)d_in[6];
    const float* bt0 = (const float*)d_in[7];
    const float* W1  = (const float*)d_in[8];
    const float* as1 = (const float*)d_in[9];
    const float* ad1 = (const float*)d_in[10];
    const float* b1  = (const float*)d_in[11];
    const float* g1  = (const float*)d_in[12];
    const float* bt1 = (const float*)d_in[13];
    const float* W2  = (const float*)d_in[14];
    const float* as2 = (const float*)d_in[15];
    const float* ad2 = (const float*)d_in[16];
    const float* b2  = (const float*)d_in[17];
    const float* lng = (const float*)d_in[18];
    const float* lnb = (const float*)d_in[19];

    const int N = in_sizes[0] / 128;
    const int E = in_sizes[1] / 2;
    const int nb = (N + 127) >> 7;     // buckets of 128 nodes (requires nb <= 1024)

    char* p = (char*)d_ws;
    auto carve = [&](size_t bytes) {
        void* q = (void*)p;
        p += (bytes + 255) & ~(size_t)255;
        return q;
    };
    short* Hb     = (short*)carve((size_t)N * 128 * 2);
    short* aggb   = (short*)carve((size_t)N * 128 * 2);
    short* x1b    = (short*)carve((size_t)N * 128 * 2);
    float* als    = (float*)carve((size_t)N * 8 * 4);
    float* ald    = (float*)carve((size_t)N * 8 * 4);
    int*   rowptr = (int*)carve((size_t)N * 4);
    int*   rowend = (int*)carve((size_t)N * 4);
    float* part0  = (float*)carve(64 * 256 * 4);
    float* part1  = (float*)carve(64 * 256 * 4);
    int*   col    = (int*)carve((size_t)nb * CSTRIDE * 4);
    int2*  ebin   = (int2*)carve((size_t)nb * ESTRIDE * 8);
    int*   bcursor= (int*)carve(1024 * 4);
    short* Wt0    = (short*)carve(144 * 128 * 2);
    short* Wt1    = (short*)carve(144 * 128 * 2);
    short* Wt2    = (short*)carve(80 * 128 * 2);

    const float invN = 1.f / (float)N;
    const int bb = (E + 256 * EPT - 1) / (256 * EPT);

    k_wprep<<<128, 256, 0, stream>>>(W0, W1, W2, as0, ad0, as1, ad1, as2, ad2,
                                     Wt0, Wt1, Wt2, part0, part1, bcursor);
    k_bin<<<bb, 256, 0, stream>>>(ei, ei + E, E, nb, bcursor, ebin);
    k_cfill2<<<nb, 256, 0, stream>>>(bcursor, ebin, rowptr, rowend, col, N);

    const int gb = (N + 127) / 128;
    const int ab = (N + 7) / 8;

    // ---- layer 0 ----
    k_gemm<128, false, false, false><<<gb, 256, 0, stream>>>(
        x, Wt0, Hb, nullptr, nullptr, als, ald, N, nullptr, nullptr, nullptr, 0.f);
    k_agg<<<ab, 256, 0, stream>>>(rowptr, rowend, col, Hb, als, ald, b0, aggb, part0, N);

    // ---- layer 1 (BN stats reduce + apply fused into GEMM; agg/x1 bf16) ----
    k_gemm<128, true, false, true><<<gb, 256, 0, stream>>>(
        aggb, Wt1, Hb, x, x1b, als, ald, N, part0, g0, bt0, invN);
    k_agg<<<ab, 256, 0, stream>>>(rowptr, rowend, col, Hb, als, ald, b1, aggb, part1, N);

    // ---- layer 2 (BN fused; bf16 residual; x2 never materialized) ----
    k_gemm<64, true, true, false><<<gb, 256, 0, stream>>>(
        aggb, Wt2, Hb, x1b, nullptr, als, ald, N, part1, g1, bt1, invN);
    k_agg2ln<<<ab, 256, 0, stream>>>(rowptr, rowend, col, Hb, als, ald, b2, lng, lnb,
                                     (float*)d_out, N);
}